// Round 7
// baseline (169.952 us; speedup 1.0000x reference)
//
#include <hip/hip_runtime.h>
#include <math.h>

#define S_    10
#define C_    48
#define HWD   64
#define M_    512
#define PADK  4
#define PAIRS 20           // S_ * N(=2)
#define YPITCH 516         // LDS pitch (516%32=4 -> only 2-way bank alias = free)
#define NB    320          // grid size (all blocks co-resident: 31KB LDS, <=128 VGPR)

// Compact gathered layout: G[(s*96 + 2*c + n)*512 + m]
// ws layout (float/uint offsets)
#define OFF_GY  0
#define OFF_GX  491520                    // 10*48*2*512
#define OFF_CM  (2 * 491520)              // colmax (uint-encoded floats), 10240
#define OFF_CNT (OFF_CM + PAIRS * M_)     // 20 uint pair-arrival counters
#define OFF_ALL (OFF_CNT + 20)            // 1 uint global pair-done counter
#define OFF_B1  (OFF_ALL + 1)             // grid-barrier counter 1
#define OFF_B2  (OFF_B1 + 1)              // grid-barrier counter 2
// memset range: OFF_CM .. OFF_B2 inclusive = 10240+20+1+1+1 = 10263 uints
#define MEMSET_N 10263
#define OFF_MU  (OFF_B2 + 1)              // 480 floats (written before read)
#define OFF_PL  (OFF_MU + 480)            // 20 floats (written before read)

__device__ __forceinline__ int gidx(int n, int c, int h, int w, int d) {
  return (((n * C_ + c) * HWD + h) * HWD + w) * HWD + d;
}

// Hand-rolled grid barrier: all NB blocks must be co-resident (they are:
// 31KB LDS, launch_bounds(256,4) => >=4 blocks/CU => 1024 slots >= 320).
// threadfence = agent-scope fence (L2 writeback/invalidate across XCDs).
__device__ __forceinline__ void gridbar(unsigned* ctr) {
  __syncthreads();                     // all block stores issued & drained
  if (threadIdx.x == 0) {
    __threadfence();                   // release: flush XCD L2 to LLC
    atomicAdd(ctr, 1u);
    while (atomicOr(ctr, 0u) < NB) __builtin_amdgcn_s_sleep(2);
  }
  __syncthreads();
  __threadfence();                     // acquire: invalidate stale L1/L2
}

__global__ __launch_bounds__(256, 4) void k_fused(
    const float* __restrict__ x, const float* __restrict__ y,
    const int* __restrict__ hi, const int* __restrict__ wi,
    const int* __restrict__ di, float* __restrict__ ws,
    float* __restrict__ out) {
  int b = blockIdx.x, t = threadIdx.x;
  int lane = t & 63, wv = t >> 6;
  unsigned* wsu = (unsigned*)ws;

  __shared__ float xl[C_ * 32];        // phase 3: x tile [c][row] (32 rows)
  __shared__ float yl[12 * YPITCH];    // phase 3: y chunk [c_rel][p]
  __shared__ float red4[4];
  __shared__ unsigned arr;
  __shared__ int lastflag;

  // ===== phase 1: gather x,y -> compact ws; y per-(s,c) means =============
#pragma unroll
  for (int it = 0; it < 3; ++it) {
    int slice = b + NB * it;           // 0..959 = (which, s, c)
    int which = slice >= 480;          // 0 = y, 1 = x (block-uniform)
    int r = which ? slice - 480 : slice;
    int s = r / C_, c = r % C_;
    const float* src = which ? x : y;
    int h0 = hi[s] - PADK, w0 = wi[s] - PADK, d0 = di[s] - PADK;
    float* dst = ws + (which ? OFF_GX : OFF_GY) + (s * 96 + 2 * c) * 512;
    float sum = 0.f;
#pragma unroll
    for (int j = 0; j < 4; ++j) {
      int i = t + 256 * j;             // 0..1023 over (n,m)
      int n = i >> 9, m = i & 511;
      float v = src[gidx(n, c, h0 + (m >> 6), w0 + ((m >> 3) & 7), d0 + (m & 7))];
      dst[n * 512 + m] = v;            // coalesced compact store
      sum += v;
    }
    if (!which) {
#pragma unroll
      for (int off = 32; off; off >>= 1) sum += __shfl_xor(sum, off);
      __syncthreads();                 // protect red4 reuse across iterations
      if (lane == 0) red4[wv] = sum;
      __syncthreads();
      if (t == 0)
        ws[OFF_MU + s * C_ + c] =
            (red4[0] + red4[1] + red4[2] + red4[3]) * (1.0f / 1024.0f);
    }
  }
  gridbar(wsu + OFF_B1);

  // ===== phase 2: center + L2-normalize in place (4 lanes per column) =====
  {
    int g = b * 256 + t;               // 0..81919
    int col = g >> 2;                  // 0..20479
    int q = t & 3;                     // channel quarter
    int which = col >= 10240;          // 0 = y, 1 = x
    int cix = which ? col - 10240 : col;
    int pair = cix >> 9, m = cix & 511;
    int s = pair >> 1, n = pair & 1;
    float* base2 = ws + (which ? OFF_GX : OFF_GY) + (s * 96 + n) * 512 + m;
    const float* mus = ws + OFF_MU + s * C_;
    int c0 = q * 12;
    float v[12], ss = 0.f;
#pragma unroll
    for (int j = 0; j < 12; ++j) {
      v[j] = base2[(c0 + j) * 1024] - mus[c0 + j];
      ss += v[j] * v[j];
    }
    ss += __shfl_xor(ss, 1);           // combine 4 quarters (aligned group)
    ss += __shfl_xor(ss, 2);
    float sc = 1.0f / fmaxf(sqrtf(ss), 1e-12f);
#pragma unroll
    for (int j = 0; j < 12; ++j) base2[(c0 + j) * 1024] = v[j] * sc;
  }
  gridbar(wsu + OFF_B2);

  // ===== phase 3: dist + row-softmax + column-max + fused final ===========
  int pair = b >> 4, tile = b & 15;
  int s = pair >> 1, n = pair & 1;

  const float* xsrc = ws + OFF_GX + (s * 96 + n) * 512 + tile * 32;
#pragma unroll
  for (int i = 0; i < 2; ++i) {
    int li = t + 256 * i;              // 384 float4s
    if (li < 384) {
      int c = li >> 3, r4 = (li & 7) << 2;
      *(float4*)(xl + c * 32 + r4) = *(const float4*)(xsrc + c * 1024 + r4);
    }
  }

  float acc[8][8];
#pragma unroll
  for (int r = 0; r < 8; ++r)
#pragma unroll
    for (int k = 0; k < 8; ++k) acc[r][k] = 0.f;

  const float* ysrc = ws + OFF_GY + (s * 96 + n) * 512;
  for (int chunk = 0; chunk < 4; ++chunk) {
    __syncthreads();                   // covers xl staging on first iter
#pragma unroll
    for (int i = 0; i < 6; ++i) {      // 12 channels x 512 = 1536 float4s
      int li = t + 256 * i;
      int cr = li >> 7, p4 = (li & 127) << 2;
      *(float4*)(yl + cr * YPITCH + p4) =
          *(const float4*)(ysrc + (chunk * 12 + cr) * 1024 + p4);
    }
    __syncthreads();
#pragma unroll
    for (int cr = 0; cr < 12; ++cr) {
      float yv[8];
#pragma unroll
      for (int k = 0; k < 8; ++k) yv[k] = yl[cr * YPITCH + lane + 64 * k];
      int c = chunk * 12 + cr;
#pragma unroll
      for (int r4 = 0; r4 < 2; ++r4) {
        float4 xv = *(const float4*)(xl + c * 32 + wv * 8 + r4 * 4); // broadcast
#pragma unroll
        for (int k = 0; k < 8; ++k) {
          acc[r4 * 4 + 0][k] += xv.x * yv[k];
          acc[r4 * 4 + 1][k] += xv.y * yv[k];
          acc[r4 * 4 + 2][k] += xv.z * yv[k];
          acc[r4 * 4 + 3][k] += xv.w * yv[k];
        }
      }
    }
  }

  float cmax[8];
#pragma unroll
  for (int k = 0; k < 8; ++k) cmax[k] = 0.f;
#pragma unroll
  for (int r = 0; r < 8; ++r) {
    float dmin = 3.4e38f;
#pragma unroll
    for (int k = 0; k < 8; ++k) {
      float d = 1.0f - acc[r][k];
      acc[r][k] = d;
      dmin = fminf(dmin, d);
    }
#pragma unroll
    for (int off = 32; off; off >>= 1) dmin = fminf(dmin, __shfl_xor(dmin, off));
    float inv = 2.0f / (dmin + 1e-5f); // logits <= 2, no overflow
    float e[8], sm = 0.f;
#pragma unroll
    for (int k = 0; k < 8; ++k) {
      e[k] = __expf(2.0f - acc[r][k] * inv);
      sm += e[k];
    }
#pragma unroll
    for (int off = 32; off; off >>= 1) sm += __shfl_xor(sm, off);
    float rs = 1.0f / sm;
#pragma unroll
    for (int k = 0; k < 8; ++k) cmax[k] = fmaxf(cmax[k], e[k] * rs);
  }
  unsigned* cmu = wsu + OFF_CM + pair * M_;
#pragma unroll
  for (int k = 0; k < 8; ++k)
    atomicMax(&cmu[lane + 64 * k], __float_as_uint(cmax[k]));

  // fused final: last block per pair reduces; last pair writes out
  __threadfence();
  if (t == 0) arr = atomicAdd(wsu + OFF_CNT + pair, 1u);
  __syncthreads();                     // arr block-uniform after this
  if (arr == 15) {
    float sum = __uint_as_float(atomicOr(&cmu[t], 0u)) +
                __uint_as_float(atomicOr(&cmu[t + 256], 0u));
#pragma unroll
    for (int off = 32; off; off >>= 1) sum += __shfl_xor(sum, off);
    if (lane == 0) red4[wv] = sum;
    if (t == 0) lastflag = 0;
    __syncthreads();
    if (t == 0) {
      float tot = red4[0] + red4[1] + red4[2] + red4[3];
      float loss = -logf(tot * (1.0f / 512.0f) + 1e-5f);
      atomicExch(wsu + OFF_PL + pair, __float_as_uint(loss));
      __threadfence();
      unsigned d = atomicAdd(wsu + OFF_ALL, 1u);
      if (d == PAIRS - 1) lastflag = 1;
    }
    __syncthreads();
    if (lastflag && t < 32) {          // parallel 20-loss readback
      float v = (t < PAIRS)
                    ? __uint_as_float(atomicOr(wsu + OFF_PL + t, 0u))
                    : 0.f;
#pragma unroll
      for (int off = 16; off; off >>= 1) v += __shfl_xor(v, off);
      if (t == 0) out[0] = v * (1.0f / (float)PAIRS);
    }
  }
}

extern "C" void kernel_launch(void* const* d_in, const int* in_sizes, int n_in,
                              void* d_out, int out_size, void* d_ws, size_t ws_size,
                              hipStream_t stream) {
  const float* x = (const float*)d_in[0];
  const float* y = (const float*)d_in[1];
  const int* hi = (const int*)d_in[2];
  const int* wi = (const int*)d_in[3];
  const int* di = (const int*)d_in[4];
  float* ws = (float*)d_ws;
  float* out = (float*)d_out;

  // zero colmax + all sync counters (graph-capturable, replay-deterministic)
  hipMemsetAsync(ws + OFF_CM, 0, MEMSET_N * sizeof(float), stream);
  k_fused<<<NB, 256, 0, stream>>>(x, y, hi, wi, di, ws, out);
}

// Round 8
// 48.811 us; speedup vs baseline: 3.4818x; 3.4818x over previous
//
#include <hip/hip_runtime.h>
#include <math.h>

#define S_    10
#define C_    48
#define HWD   64
#define M_    512
#define PADK  4
#define PAIRS 20           // S_ * N(=2)
#define YPITCH 516         // LDS pitch (516%32=4 -> only 2-way bank alias = free)

// Compact gathered layout: G[(s*96 + 2*c + n)*512 + m]
// ws layout (float offsets)
#define OFF_GY  0
#define OFF_GX  491520                    // 10*48*2*512
#define OFF_CM  (2 * 491520)              // colmax (uint-encoded floats), 10240
#define OFF_MU  (OFF_CM + PAIRS * M_)     // 480 floats
#define OFF_CNT (OFF_MU + 480)            // 20 uint pair-arrival counters
#define OFF_ALL (OFF_CNT + 20)            // 1 uint global pair-done counter
#define OFF_PL  (OFF_ALL + 1)             // 20 float pair losses

__device__ __forceinline__ int gidx(int n, int c, int h, int w, int d) {
  return (((n * C_ + c) * HWD + h) * HWD + w) * HWD + d;
}

// ---- kernel 1: gather x,y -> compact ws; fold y channel-mean --------------
// 960 blocks x 256 thr; block = (which, s, c); 4 elems/thread => 3840 waves
// of MLP for the scattered HBM reads (this was 960 waves in R4 - the
// latency bottleneck).
__global__ void k_gather(const float* __restrict__ x, const float* __restrict__ y,
                         const int* __restrict__ hi, const int* __restrict__ wi,
                         const int* __restrict__ di, float* __restrict__ ws) {
  int b = blockIdx.x, t = threadIdx.x;
  int lane = t & 63, wv = t >> 6;
  __shared__ float red[4];
  if (b < 40) ws[OFF_CM + b * 256 + t] = 0.f;        // zero colmax (10240)
  if (b == 40 && t < 41) ws[OFF_CNT + t] = 0.f;      // zero counters + losses
  int which = b >= 480;                              // 0 = y, 1 = x
  int r = which ? b - 480 : b;
  int s = r / C_, c = r % C_;
  const float* src = which ? x : y;
  int h0 = hi[s] - PADK, w0 = wi[s] - PADK, d0 = di[s] - PADK;
  float* dst = ws + (which ? OFF_GX : OFF_GY) + (s * 96 + 2 * c) * 512;
  float sum = 0.f;
#pragma unroll
  for (int j = 0; j < 4; ++j) {
    int i = t + 256 * j;             // 0..1023 over (n,m); 4 loads in flight
    int n = i >> 9, m = i & 511;
    float v = src[gidx(n, c, h0 + (m >> 6), w0 + ((m >> 3) & 7), d0 + (m & 7))];
    dst[n * 512 + m] = v;            // coalesced compact store
    sum += v;
  }
  if (!which) {                      // block-uniform branch
#pragma unroll
    for (int off = 32; off; off >>= 1) sum += __shfl_xor(sum, off);
    if (lane == 0) red[wv] = sum;
    __syncthreads();
    if (t == 0)
      ws[OFF_MU + s * C_ + c] =
          (red[0] + red[1] + red[2] + red[3]) * (1.0f / 1024.0f);
  }
}

// ---- kernel 2: center + L2-normalize IN PLACE on the compact buffer -------
// 320 blocks x 256 thr; 4 lanes per column (12 channels each). L2-resident.
__global__ void k_norm2(float* __restrict__ ws) {
  int g = blockIdx.x * 256 + threadIdx.x;   // 0..81919
  int col = g >> 2;                         // 0..20479
  int q = threadIdx.x & 3;                  // channel quarter
  int which = col >= 10240;                 // 0 = y, 1 = x
  int cix = which ? col - 10240 : col;
  int pair = cix >> 9, m = cix & 511;
  int s = pair >> 1, n = pair & 1;
  float* base = ws + (which ? OFF_GX : OFF_GY) + (s * 96 + n) * 512 + m;
  const float* mus = ws + OFF_MU + s * C_;
  int c0 = q * 12;
  float v[12];
  float ss = 0.f;
#pragma unroll
  for (int j = 0; j < 12; ++j) {
    v[j] = base[(c0 + j) * 1024] - mus[c0 + j];
    ss += v[j] * v[j];
  }
  // combine the 4 quarters of this column (aligned 4-lane group)
  ss += __shfl_xor(ss, 1);
  ss += __shfl_xor(ss, 2);
  float sc = 1.0f / fmaxf(sqrtf(ss), 1e-12f);
#pragma unroll
  for (int j = 0; j < 12; ++j) base[(c0 + j) * 1024] = v[j] * sc;
}

// ---- kernel 3: dist + row-softmax + column-max + fused final --------------
// 320 blocks x 256 thr; block = (pair, tile of 32 rows); 8 rows/wave.
__global__ __launch_bounds__(256, 4) void k_main(float* __restrict__ ws,
                                                 float* __restrict__ out) {
  int b = blockIdx.x;
  int pair = b >> 4, tile = b & 15;
  int s = pair >> 1, n = pair & 1;
  int t = threadIdx.x, lane = t & 63, wv = t >> 6;

  __shared__ float xl[C_ * 32];        // x tile: [c][row] (32 rows)
  __shared__ float yl[12 * YPITCH];    // y chunk: [c_rel][p]

  const float* xsrc = ws + OFF_GX + (s * 96 + n) * 512 + tile * 32;
#pragma unroll
  for (int i = 0; i < 2; ++i) {
    int li = t + 256 * i;              // 384 float4s
    if (li < 384) {
      int c = li >> 3, r4 = (li & 7) << 2;
      *(float4*)(xl + c * 32 + r4) = *(const float4*)(xsrc + c * 1024 + r4);
    }
  }

  float acc[8][8];
#pragma unroll
  for (int r = 0; r < 8; ++r)
#pragma unroll
    for (int k = 0; k < 8; ++k) acc[r][k] = 0.f;

  const float* ysrc = ws + OFF_GY + (s * 96 + n) * 512;
  for (int chunk = 0; chunk < 4; ++chunk) {
    __syncthreads();
#pragma unroll
    for (int i = 0; i < 6; ++i) {      // 12 channels x 512 = 1536 float4s
      int li = t + 256 * i;
      int cr = li >> 7, p4 = (li & 127) << 2;
      *(float4*)(yl + cr * YPITCH + p4) =
          *(const float4*)(ysrc + (chunk * 12 + cr) * 1024 + p4);
    }
    __syncthreads();
#pragma unroll
    for (int cr = 0; cr < 12; ++cr) {
      float yv[8];
#pragma unroll
      for (int k = 0; k < 8; ++k) yv[k] = yl[cr * YPITCH + lane + 64 * k];
      int c = chunk * 12 + cr;
#pragma unroll
      for (int r4 = 0; r4 < 2; ++r4) {
        float4 xv = *(const float4*)(xl + c * 32 + wv * 8 + r4 * 4); // broadcast
#pragma unroll
        for (int k = 0; k < 8; ++k) {
          acc[r4 * 4 + 0][k] += xv.x * yv[k];
          acc[r4 * 4 + 1][k] += xv.y * yv[k];
          acc[r4 * 4 + 2][k] += xv.z * yv[k];
          acc[r4 * 4 + 3][k] += xv.w * yv[k];
        }
      }
    }
  }

  // epilogue: per row min -> softmax over p -> column-max accumulate
  float cmax[8];
#pragma unroll
  for (int k = 0; k < 8; ++k) cmax[k] = 0.f;
#pragma unroll
  for (int r = 0; r < 8; ++r) {
    float dmin = 3.4e38f;
#pragma unroll
    for (int k = 0; k < 8; ++k) {
      float d = 1.0f - acc[r][k];
      acc[r][k] = d;
      dmin = fminf(dmin, d);
    }
#pragma unroll
    for (int off = 32; off; off >>= 1) dmin = fminf(dmin, __shfl_xor(dmin, off));
    float inv = 2.0f / (dmin + 1e-5f);  // logits <= 2, no overflow
    float e[8], sm = 0.f;
#pragma unroll
    for (int k = 0; k < 8; ++k) {
      e[k] = __expf(2.0f - acc[r][k] * inv);
      sm += e[k];
    }
#pragma unroll
    for (int off = 32; off; off >>= 1) sm += __shfl_xor(sm, off);
    float rs = 1.0f / sm;
#pragma unroll
    for (int k = 0; k < 8; ++k) cmax[k] = fmaxf(cmax[k], e[k] * rs);
  }
  unsigned* cmu = (unsigned*)(ws + OFF_CM) + pair * M_;
#pragma unroll
  for (int k = 0; k < 8; ++k)
    atomicMax(&cmu[lane + 64 * k], __float_as_uint(cmax[k]));

  // ---- fused final: last block per pair reduces; last pair writes out ----
  __threadfence();
  __shared__ unsigned arr;
  __shared__ float red[4];
  __shared__ int lastflag;
  if (t == 0) arr = atomicAdd((unsigned*)(ws + OFF_CNT) + pair, 1u);
  __syncthreads();
  if (arr == 15) {
    float sum = __uint_as_float(atomicOr(&cmu[t], 0u)) +
                __uint_as_float(atomicOr(&cmu[t + 256], 0u));
#pragma unroll
    for (int off = 32; off; off >>= 1) sum += __shfl_xor(sum, off);
    if (lane == 0) red[wv] = sum;
    if (t == 0) lastflag = 0;
    __syncthreads();
    if (t == 0) {
      float tot = red[0] + red[1] + red[2] + red[3];
      float loss = -logf(tot * (1.0f / 512.0f) + 1e-5f);
      atomicExch((unsigned*)(ws + OFF_PL) + pair, __float_as_uint(loss));
      __threadfence();
      unsigned d = atomicAdd((unsigned*)(ws + OFF_ALL), 1u);
      if (d == PAIRS - 1) lastflag = 1;
    }
    __syncthreads();
    if (lastflag && t < 32) {          // parallel 20-loss readback
      float v = (t < PAIRS)
                    ? __uint_as_float(atomicOr((unsigned*)(ws + OFF_PL) + t, 0u))
                    : 0.f;
#pragma unroll
      for (int off = 16; off; off >>= 1) v += __shfl_xor(v, off);
      if (t == 0) out[0] = v * (1.0f / (float)PAIRS);
    }
  }
}

extern "C" void kernel_launch(void* const* d_in, const int* in_sizes, int n_in,
                              void* d_out, int out_size, void* d_ws, size_t ws_size,
                              hipStream_t stream) {
  const float* x = (const float*)d_in[0];
  const float* y = (const float*)d_in[1];
  const int* hi = (const int*)d_in[2];
  const int* wi = (const int*)d_in[3];
  const int* di = (const int*)d_in[4];
  float* ws = (float*)d_ws;
  float* out = (float*)d_out;

  k_gather<<<960, 256, 0, stream>>>(x, y, hi, wi, di, ws);
  k_norm2<<<320, 256, 0, stream>>>(ws);
  k_main<<<PAIRS * 16, 256, 0, stream>>>(ws, out);
}

// Round 9
// 48.573 us; speedup vs baseline: 3.4989x; 1.0049x over previous
//
#include <hip/hip_runtime.h>
#include <math.h>

#define S_    10
#define C_    48
#define HWD   64
#define M_    512
#define PADK  4
#define PAIRS 20           // S_ * N(=2)
#define YPITCH 516         // LDS pitch (516%32=4 -> only 2-way bank alias = free)

// Compact gathered layout: G[(s*96 + 2*c + n)*512 + m]
// ws layout (float offsets)
#define OFF_GY  0
#define OFF_GX  491520                    // 10*48*2*512
#define OFF_CM  (2 * 491520)              // colmax (uint-encoded floats), 10240
#define OFF_MU  (OFF_CM + PAIRS * M_)     // 480 floats
#define OFF_CNT (OFF_MU + 480)            // 20 uint pair-arrival counters
#define OFF_ALL (OFF_CNT + 20)            // 1 uint global pair-done counter
#define OFF_PL  (OFF_ALL + 1)             // 20 float pair losses

__device__ __forceinline__ int gidx(int n, int c, int h, int w, int d) {
  return (((n * C_ + c) * HWD + h) * HWD + w) * HWD + d;
}

// ---- kernel 1: gather x,y -> compact ws; fold y channel-mean --------------
// 960 blocks x 256 thr; block = (which, s, c); 4 elems/thread.
__global__ void k_gather(const float* __restrict__ x, const float* __restrict__ y,
                         const int* __restrict__ hi, const int* __restrict__ wi,
                         const int* __restrict__ di, float* __restrict__ ws) {
  int b = blockIdx.x, t = threadIdx.x;
  int lane = t & 63, wv = t >> 6;
  __shared__ float red[4];
  if (b < 40) ws[OFF_CM + b * 256 + t] = 0.f;        // zero colmax (10240)
  if (b == 40 && t < 41) ws[OFF_CNT + t] = 0.f;      // zero counters + losses
  int which = b >= 480;                              // 0 = y, 1 = x
  int r = which ? b - 480 : b;
  int s = r / C_, c = r % C_;
  const float* src = which ? x : y;
  int h0 = hi[s] - PADK, w0 = wi[s] - PADK, d0 = di[s] - PADK;
  float* dst = ws + (which ? OFF_GX : OFF_GY) + (s * 96 + 2 * c) * 512;
  float sum = 0.f;
#pragma unroll
  for (int j = 0; j < 4; ++j) {
    int i = t + 256 * j;             // 0..1023 over (n,m); 4 loads in flight
    int n = i >> 9, m = i & 511;
    float v = src[gidx(n, c, h0 + (m >> 6), w0 + ((m >> 3) & 7), d0 + (m & 7))];
    dst[n * 512 + m] = v;            // coalesced compact store
    sum += v;
  }
  if (!which) {                      // block-uniform branch
#pragma unroll
    for (int off = 32; off; off >>= 1) sum += __shfl_xor(sum, off);
    if (lane == 0) red[wv] = sum;
    __syncthreads();
    if (t == 0)
      ws[OFF_MU + s * C_ + c] =
          (red[0] + red[1] + red[2] + red[3]) * (1.0f / 1024.0f);
  }
}

// ---- kernel 2: center + L2-normalize IN PLACE on the compact buffer -------
// 320 blocks x 256 thr; 4 lanes per column (12 channels each). L2-resident.
__global__ void k_norm2(float* __restrict__ ws) {
  int g = blockIdx.x * 256 + threadIdx.x;   // 0..81919
  int col = g >> 2;                         // 0..20479
  int q = threadIdx.x & 3;                  // channel quarter
  int which = col >= 10240;                 // 0 = y, 1 = x
  int cix = which ? col - 10240 : col;
  int pair = cix >> 9, m = cix & 511;
  int s = pair >> 1, n = pair & 1;
  float* base = ws + (which ? OFF_GX : OFF_GY) + (s * 96 + n) * 512 + m;
  const float* mus = ws + OFF_MU + s * C_;
  int c0 = q * 12;
  float v[12];
  float ss = 0.f;
#pragma unroll
  for (int j = 0; j < 12; ++j) {
    v[j] = base[(c0 + j) * 1024] - mus[c0 + j];
    ss += v[j] * v[j];
  }
  // combine the 4 quarters of this column (aligned 4-lane group)
  ss += __shfl_xor(ss, 1);
  ss += __shfl_xor(ss, 2);
  float sc = 1.0f / fmaxf(sqrtf(ss), 1e-12f);
#pragma unroll
  for (int j = 0; j < 12; ++j) base[(c0 + j) * 1024] = v[j] * sc;
}

// ---- kernel 3: dist + row-softmax + column-max + fused final --------------
// 320 blocks x 256 thr; block = (pair, tile of 32 rows); 8 rows/wave.
// launch_bounds(256,2): VGPR cap 256 so acc[8][8] stays in arch VGPRs.
// (256,4) capped VGPRs at 64 -> acc spilled to AGPR/scratch -> 3x inner loop.
// 320 blocks only need 1.25 blocks/CU, so occupancy 2 is plenty.
__global__ __launch_bounds__(256, 2) void k_main(float* __restrict__ ws,
                                                 float* __restrict__ out) {
  int b = blockIdx.x;
  int pair = b >> 4, tile = b & 15;
  int s = pair >> 1, n = pair & 1;
  int t = threadIdx.x, lane = t & 63, wv = t >> 6;

  __shared__ float xl[C_ * 32];        // x tile: [c][row] (32 rows)
  __shared__ float yl[12 * YPITCH];    // y chunk: [c_rel][p]

  const float* xsrc = ws + OFF_GX + (s * 96 + n) * 512 + tile * 32;
#pragma unroll
  for (int i = 0; i < 2; ++i) {
    int li = t + 256 * i;              // 384 float4s
    if (li < 384) {
      int c = li >> 3, r4 = (li & 7) << 2;
      *(float4*)(xl + c * 32 + r4) = *(const float4*)(xsrc + c * 1024 + r4);
    }
  }

  float acc[8][8];
#pragma unroll
  for (int r = 0; r < 8; ++r)
#pragma unroll
    for (int k = 0; k < 8; ++k) acc[r][k] = 0.f;

  const float* ysrc = ws + OFF_GY + (s * 96 + n) * 512;
  for (int chunk = 0; chunk < 4; ++chunk) {
    __syncthreads();
#pragma unroll
    for (int i = 0; i < 6; ++i) {      // 12 channels x 512 = 1536 float4s
      int li = t + 256 * i;
      int cr = li >> 7, p4 = (li & 127) << 2;
      *(float4*)(yl + cr * YPITCH + p4) =
          *(const float4*)(ysrc + (chunk * 12 + cr) * 1024 + p4);
    }
    __syncthreads();
#pragma unroll
    for (int cr = 0; cr < 12; ++cr) {
      float yv[8];
#pragma unroll
      for (int k = 0; k < 8; ++k) yv[k] = yl[cr * YPITCH + lane + 64 * k];
      int c = chunk * 12 + cr;
#pragma unroll
      for (int r4 = 0; r4 < 2; ++r4) {
        float4 xv = *(const float4*)(xl + c * 32 + wv * 8 + r4 * 4); // broadcast
#pragma unroll
        for (int k = 0; k < 8; ++k) {
          acc[r4 * 4 + 0][k] += xv.x * yv[k];
          acc[r4 * 4 + 1][k] += xv.y * yv[k];
          acc[r4 * 4 + 2][k] += xv.z * yv[k];
          acc[r4 * 4 + 3][k] += xv.w * yv[k];
        }
      }
    }
  }

  // epilogue: per row min -> softmax over p -> column-max accumulate
  float cmax[8];
#pragma unroll
  for (int k = 0; k < 8; ++k) cmax[k] = 0.f;
#pragma unroll
  for (int r = 0; r < 8; ++r) {
    float dmin = 3.4e38f;
#pragma unroll
    for (int k = 0; k < 8; ++k) {
      float d = 1.0f - acc[r][k];
      acc[r][k] = d;
      dmin = fminf(dmin, d);
    }
#pragma unroll
    for (int off = 32; off; off >>= 1) dmin = fminf(dmin, __shfl_xor(dmin, off));
    float inv = 2.0f / (dmin + 1e-5f);  // logits <= 2, no overflow
    float e[8], sm = 0.f;
#pragma unroll
    for (int k = 0; k < 8; ++k) {
      e[k] = __expf(2.0f - acc[r][k] * inv);
      sm += e[k];
    }
#pragma unroll
    for (int off = 32; off; off >>= 1) sm += __shfl_xor(sm, off);
    float rs = 1.0f / sm;
#pragma unroll
    for (int k = 0; k < 8; ++k) cmax[k] = fmaxf(cmax[k], e[k] * rs);
  }
  unsigned* cmu = (unsigned*)(ws + OFF_CM) + pair * M_;
#pragma unroll
  for (int k = 0; k < 8; ++k)
    atomicMax(&cmu[lane + 64 * k], __float_as_uint(cmax[k]));

  // ---- fused final: last block per pair reduces; last pair writes out ----
  __threadfence();
  __shared__ unsigned arr;
  __shared__ float red[4];
  __shared__ int lastflag;
  if (t == 0) arr = atomicAdd((unsigned*)(ws + OFF_CNT) + pair, 1u);
  __syncthreads();
  if (arr == 15) {
    float sum = __uint_as_float(atomicOr(&cmu[t], 0u)) +
                __uint_as_float(atomicOr(&cmu[t + 256], 0u));
#pragma unroll
    for (int off = 32; off; off >>= 1) sum += __shfl_xor(sum, off);
    if (lane == 0) red[wv] = sum;
    if (t == 0) lastflag = 0;
    __syncthreads();
    if (t == 0) {
      float tot = red[0] + red[1] + red[2] + red[3];
      float loss = -logf(tot * (1.0f / 512.0f) + 1e-5f);
      atomicExch((unsigned*)(ws + OFF_PL) + pair, __float_as_uint(loss));
      __threadfence();
      unsigned d = atomicAdd((unsigned*)(ws + OFF_ALL), 1u);
      if (d == PAIRS - 1) lastflag = 1;
    }
    __syncthreads();
    if (lastflag && t < 32) {          // parallel 20-loss readback
      float v = (t < PAIRS)
                    ? __uint_as_float(atomicOr((unsigned*)(ws + OFF_PL) + t, 0u))
                    : 0.f;
#pragma unroll
      for (int off = 16; off; off >>= 1) v += __shfl_xor(v, off);
      if (t == 0) out[0] = v * (1.0f / (float)PAIRS);
    }
  }
}

extern "C" void kernel_launch(void* const* d_in, const int* in_sizes, int n_in,
                              void* d_out, int out_size, void* d_ws, size_t ws_size,
                              hipStream_t stream) {
  const float* x = (const float*)d_in[0];
  const float* y = (const float*)d_in[1];
  const int* hi = (const int*)d_in[2];
  const int* wi = (const int*)d_in[3];
  const int* di = (const int*)d_in[4];
  float* ws = (float*)d_ws;
  float* out = (float*)d_out;

  k_gather<<<960, 256, 0, stream>>>(x, y, hi, wi, di, ws);
  k_norm2<<<320, 256, 0, stream>>>(ws);
  k_main<<<PAIRS * 16, 256, 0, stream>>>(ws, out);
}